// Round 9
// baseline (26.006 us; speedup 1.0000x reference)
//
#include <hip/hip_runtime.h>
#include <math.h>

#define EPS 1e-6f
#define LOG2E 1.4426950408889634f
// Schraudolph exp2 bias: (127 + c)*2^23, c tuned for zero-mean relative error
// over uniform mantissa fraction (range ~[-5.7%, +2.0%]). Confirmed R8.
#define SCHRAUD_K 1064878421.0f

typedef float v2f __attribute__((ext_vector_type(2)));

constexpr int TB  = 256;   // threads/block (4 waves)
constexpr int TD  = 256;   // dense tile dim (1 i-row/thread, TD j's in LDS)
constexpr int EPT = 8;     // edges per thread

// Blocks [0, ne): edge chunks. Blocks [ne, ne+nd): dense triangular tiles.
// part[] homogeneous pre-weighted: answer = sum(part).
//
// Dense inner loop: 2 pairs/iter in PACKED fp32 (ext_vector_type(2) lowers to
// v_pk_sub/mul/fma on gfx950): per 2 pairs = 4 pk (8cyc) + 2 v_sqrt (16) +
// 1 pk scale-fma (2) + 2 v_cvt (4) + 1 pk acc-fma (2) = 32 cyc vs 44 scalar.
// sqrt stays EXACT (don't stack a second approximation on Schraudolph).
__global__ void __launch_bounds__(TB) k_fused(
    const float2* __restrict__ Z, const float* __restrict__ gamma,
    const int* __restrict__ ei, const int* __restrict__ ej,
    float* __restrict__ part, int n, int nb, int ne, int e)
{
    __shared__ float4 sXY[TD / 2];   // (x_2k, x_2k+1, y_2k, y_2k+1) * LOG2E
    __shared__ float2 sW[TD / 2];    // (exp(g_2k), exp(g_2k+1))
    __shared__ float wsum[TB / 64];
    const int bx = blockIdx.x;
    float acc = 0.f;
    float blockw = 1.f;

    if (bx >= ne) {
        // ---- dense role: decode triangular index -> (a,b), b >= a ----
        const int t = bx - ne;
        auto before = [nb](int x) { return x * nb - (x * (x - 1)) / 2; };
        int a = (int)(((2 * nb + 1) -
                       sqrtf((float)((2 * nb + 1) * (2 * nb + 1) - 8 * t))) * 0.5f);
        if (a < 0) a = 0;
        if (a > nb - 1) a = nb - 1;
        while (before(a + 1) <= t) ++a;
        while (before(a) > t) --a;
        const int b = a + (t - before(a));

        const int j0 = b * TD;

        if (threadIdx.x < TD / 2) {
            const int k  = threadIdx.x;
            const int j1 = j0 + 2 * k, j2 = j1 + 1;
            float4 xy;
            float2 w;
            if (j2 < n) {
                float4 zz = *(const float4*)(&Z[j1]);   // (x1,y1,x2,y2), 16B-aligned (j1 even)
                float2 gg = *(const float2*)(&gamma[j1]);
                xy = make_float4(zz.x * LOG2E, zz.z * LOG2E,
                                 zz.y * LOG2E, zz.w * LOG2E);
                w  = make_float2(__expf(gg.x), __expf(gg.y));
            } else {
                int c1 = j1 < n ? j1 : n - 1;
                int c2 = j2 < n ? j2 : n - 1;
                float2 z1 = Z[c1], z2 = Z[c2];
                xy = make_float4(z1.x * LOG2E, z2.x * LOG2E,
                                 z1.y * LOG2E, z2.y * LOG2E);
                w  = make_float2(j1 < n ? __expf(gamma[c1]) : 0.f,
                                 j2 < n ? __expf(gamma[c2]) : 0.f);
            }
            sXY[k] = xy;
            sW[k]  = w;
        }
        __syncthreads();

        const int i = a * TD + threadIdx.x;
        if (i < n) {
            float2 zi = Z[i];
            const float ax = (zi.x + EPS) * LOG2E;
            const float ay = (zi.y + EPS) * LOG2E;
            const v2f axv = {ax, ax};
            const v2f ayv = {ay, ay};
            const v2f mneg = {-8388608.f, -8388608.f};
            const v2f kv   = {SCHRAUD_K, SCHRAUD_K};
            v2f accv = {0.f, 0.f};
            #pragma unroll 8
            for (int k = 0; k < TD / 2; ++k) {
                float4 p = sXY[k];
                float2 w = sW[k];
                v2f px = {p.x, p.y}, py = {p.z, p.w};
                v2f wv = {w.x, w.y};
                v2f dx = axv - px;                   // v_pk_add (sub)
                v2f dy = ayv - py;
                v2f d2 = dx * dx + dy * dy;          // v_pk_mul + v_pk_fma; >= 0
                float r0 = __builtin_amdgcn_sqrtf(d2.x);   // exact trans x2
                float r1 = __builtin_amdgcn_sqrtf(d2.y);
                v2f rv = {r0, r1};
                v2f tv = rv * mneg + kv;             // v_pk_fma (schraudolph)
                v2f ev = {__int_as_float((int)tv.x), // v_cvt_i32_f32 x2
                          __int_as_float((int)tv.y)};
                accv = wv * ev + accv;               // v_pk_fma
            }
            acc = accv.x + accv.y;
            float egi = __expf(gamma[i]);
            if (a == b) {
                // subtract diag through the SAME approximant so it cancels
                float td = fmaf(1.41421356e-6f * LOG2E, -8388608.f, SCHRAUD_K);
                acc -= egi * __int_as_float((int)td);
            }
            acc *= egi;
        }
        blockw = (a == b) ? -0.5f : -1.0f;
    } else {
        // ---- edge role (latency-bound L2 gathers; exact trans) ----
        const long base = ((long)bx * TB + threadIdx.x) * EPT;
        if (base + EPT <= e) {
            int4 ia0 = *(const int4*)(ei + base);
            int4 ia1 = *(const int4*)(ei + base + 4);
            int4 ja0 = *(const int4*)(ej + base);
            int4 ja1 = *(const int4*)(ej + base + 4);
            const int as[EPT] = {ia0.x, ia0.y, ia0.z, ia0.w,
                                 ia1.x, ia1.y, ia1.z, ia1.w};
            const int bs[EPT] = {ja0.x, ja0.y, ja0.z, ja0.w,
                                 ja1.x, ja1.y, ja1.z, ja1.w};
            #pragma unroll
            for (int k = 0; k < EPT; ++k) {
                float2 za = Z[as[k]], zb = Z[bs[k]];
                float dx = za.x - zb.x + EPS;
                float dy = za.y - zb.y + EPS;
                float r = __builtin_amdgcn_sqrtf(fmaf(dx, dx, dy * dy));
                acc += gamma[as[k]] + gamma[bs[k]] - r;
            }
        } else {
            for (int k = 0; k < EPT; ++k) {
                long idx = base + k;
                if (idx < e) {
                    int ai = ei[idx], bi = ej[idx];
                    float2 za = Z[ai], zb = Z[bi];
                    float dx = za.x - zb.x + EPS;
                    float dy = za.y - zb.y + EPS;
                    float r = __builtin_amdgcn_sqrtf(fmaf(dx, dx, dy * dy));
                    acc += gamma[ai] + gamma[bi] - r;
                }
            }
        }
        blockw = 1.f;
    }

    // fixed-order deterministic block reduction
    for (int off = 32; off > 0; off >>= 1) acc += __shfl_down(acc, off, 64);
    const int lane = threadIdx.x & 63, w = threadIdx.x >> 6;
    if (lane == 0) wsum[w] = acc;
    __syncthreads();
    if (threadIdx.x == 0) {
        float s = 0.f;
        #pragma unroll
        for (int k = 0; k < TB / 64; ++k) s += wsum[k];
        part[bx] = blockw * s;
    }
}

// Final: out[0] = sum(part) in fp64, single wave, fixed lane-strided order +
// shuffle butterfly (deterministic).
__global__ void __launch_bounds__(64) k_final(
    const float* __restrict__ part, int np, float* __restrict__ out)
{
    double sd = 0.0;
    for (int t = threadIdx.x; t < np; t += 64) sd += (double)part[t];
    for (int off = 32; off > 0; off >>= 1) sd += __shfl_down(sd, off, 64);
    if (threadIdx.x == 0) out[0] = (float)sd;
}

extern "C" void kernel_launch(void* const* d_in, const int* in_sizes, int n_in,
                              void* d_out, int out_size, void* d_ws, size_t ws_size,
                              hipStream_t stream)
{
    const float2* Z     = (const float2*)d_in[0];
    const float*  gamma = (const float*)d_in[1];
    const int*    ei    = (const int*)d_in[2];
    const int*    ej    = (const int*)d_in[3];
    const int n = in_sizes[1];
    const int e = in_sizes[2];
    float* out = (float*)d_out;

    const int nb = (n + TD - 1) / TD;
    const int nd = nb * (nb + 1) / 2;
    const int ne = (e + TB * EPT - 1) / (TB * EPT);
    const int np = ne + nd;

    float* part = (float*)d_ws;

    hipLaunchKernelGGL(k_fused, dim3(np), dim3(TB), 0, stream,
                       Z, gamma, ei, ej, part, n, nb, ne, e);
    hipLaunchKernelGGL(k_final, dim3(1), dim3(64), 0, stream,
                       part, np, out);
}